// Round 5
// baseline (609.598 us; speedup 1.0000x reference)
//
#include <hip/hip_runtime.h>
#include <hip/hip_bf16.h>

#define S_LEN 2048
#define HDIM 3584
#define NH 28
#define NKV 4
#define HD 128
#define NQD 3584   // NH*HD
#define NKVD 512   // NKV*HD
#define NQKV 4608  // NQD + 2*NKVD

typedef __bf16 bf16x8 __attribute__((ext_vector_type(8)));
typedef float f32x4 __attribute__((ext_vector_type(4)));
typedef unsigned short u16x8 __attribute__((ext_vector_type(8)));

__device__ __forceinline__ unsigned short f2bf(float f) {
  unsigned u = __builtin_bit_cast(unsigned, f);
  u += 0x7fffu + ((u >> 16) & 1u);   // RNE
  return (unsigned short)(u >> 16);
}

__device__ __forceinline__ bf16x8 ld_frag(const unsigned short* p) {
  union { u16x8 u; bf16x8 b; } cv;
  cv.u = *(const u16x8*)p;   // 16B ds_read_b128
  return cv.b;
}

// 16x16x16 bf16 MFMA: B-operand k=quad*4+j matches S^T C-layout row=quad*4+r,
// so P feeds PV directly from registers (no cross-lane shuffle).
__device__ __forceinline__ f32x4 mfma16(unsigned alo, unsigned ahi,
                                        unsigned blo, unsigned bhi, f32x4 c) {
#if __has_builtin(__builtin_amdgcn_mfma_f32_16x16x16_bf16)
  typedef __bf16 b4 __attribute__((ext_vector_type(4)));
  union { unsigned u[2]; b4 v; } a, b;
  a.u[0] = alo; a.u[1] = ahi; b.u[0] = blo; b.u[1] = bhi;
  return __builtin_amdgcn_mfma_f32_16x16x16_bf16(a.v, b.v, c, 0, 0, 0);
#else
  typedef short s4 __attribute__((ext_vector_type(4)));
  union { unsigned u[2]; s4 v; } a, b;
  a.u[0] = alo; a.u[1] = ahi; b.u[0] = blo; b.u[1] = bhi;
  return __builtin_amdgcn_mfma_f32_16x16x16bf16_1k(a.v, b.v, c, 0, 0, 0);
#endif
}

// async global->LDS, 16B per lane; lds dest is wave-uniform base + lane*16
__device__ __forceinline__ void async_cp16(const void* g, void* lds) {
  __builtin_amdgcn_global_load_lds(
      (const __attribute__((address_space(1))) unsigned int*)g,
      (__attribute__((address_space(3))) unsigned int*)lds, 16, 0, 0);
}

// ---------------- fp32 -> bf16 flat convert ----------------
__global__ __launch_bounds__(256) void cvt_kernel(const float* __restrict__ in,
                                                  unsigned short* __restrict__ out, int n4) {
  int i = blockIdx.x * 256 + threadIdx.x;
  if (i >= n4) return;
  float4 v = ((const float4*)in)[i];
  ushort4 o;
  o.x = f2bf(v.x); o.y = f2bf(v.y); o.z = f2bf(v.z); o.w = f2bf(v.w);
  ((ushort4*)out)[i] = o;
}

// ---------------- tiled transpose + fp32->bf16: out[c][r] = in[r][c] ----------------
__global__ __launch_bounds__(256) void tcvt(const float* __restrict__ in,
                                            unsigned short* __restrict__ out,
                                            int R, int C, int ldin) {
  __shared__ float t[32][33];
  const int tx = threadIdx.x, ty = threadIdx.y;   // 32 x 8
  const int r0 = blockIdx.y * 32, c0 = blockIdx.x * 32;
#pragma unroll
  for (int j = 0; j < 4; ++j)
    t[ty + 8 * j][tx] = in[(size_t)(r0 + ty + 8 * j) * ldin + c0 + tx];
  __syncthreads();
#pragma unroll
  for (int j = 0; j < 4; ++j)
    out[(size_t)(c0 + ty + 8 * j) * R + r0 + tx] = f2bf(t[tx][ty + 8 * j]);
}

// ---------------- concat bias [bq | bk | bv] ----------------
__global__ void biascat(const float* __restrict__ bq, const float* __restrict__ bk,
                        const float* __restrict__ bv, float* __restrict__ o) {
  int i = blockIdx.x * 256 + threadIdx.x;
  if (i < NQD) o[i] = bq[i];
  else if (i < NQD + NKVD) o[i] = bk[i - NQD];
  else if (i < NQKV) o[i] = bv[i - NQD - NKVD];
}

// ---------------- mrope'd cos/sin, transposed via LDS tiles (coalesced both sides) ----
// sections: [0,16)=0 [16,40)=1 [40,64)=2 [64,80)=0 [80,104)=1 [104,128)=2
__global__ __launch_bounds__(256) void tcs_kernel(const float* __restrict__ cosp,
                                                  const float* __restrict__ sinp,
                                                  float* __restrict__ cmT,
                                                  float* __restrict__ smT) {
  __shared__ float tc[32][33], ts[32][33];
  const int tx = threadIdx.x, ty = threadIdx.y;   // 32 x 8
  const int s0 = blockIdx.x * 32, d0 = blockIdx.y * 32;
  const int d = d0 + tx;
  const int sec = d < 16 ? 0 : d < 40 ? 1 : d < 64 ? 2 : d < 80 ? 0 : d < 104 ? 1 : 2;
#pragma unroll
  for (int j = 0; j < 4; ++j) {
    size_t src = ((size_t)sec * S_LEN + s0 + ty + 8 * j) * HD + d;
    tc[ty + 8 * j][tx] = cosp[src];
    ts[ty + 8 * j][tx] = sinp[src];
  }
  __syncthreads();
#pragma unroll
  for (int j = 0; j < 4; ++j) {
    size_t dst = (size_t)(d0 + ty + 8 * j) * S_LEN + s0 + tx;
    cmT[dst] = tc[tx][ty + 8 * j];
    smT[dst] = ts[tx][ty + 8 * j];
  }
}

// ---------------- 128x128 bf16 GEMM, BK=64, global_load_lds staging ----------------
// Wave owns rows [wrow, wrow+64) and cols {wc2+0..31} U {wc2+64..95} (closed under ^64
// so the rope partner d^64 is register j^2 in the same lane).
// MODE 0: fp32 C out (+bias). MODE 1: fused QKV epilogue (rope q/k, transpose-cast v).
#define QSCALE (0.08838834764831845f * 1.4426950408889634f)
template <int MODE>
__global__ __launch_bounds__(256) void gemm_k64(
    const unsigned short* __restrict__ A,   // [M][K] bf16
    const unsigned short* __restrict__ Bt,  // [N][K] bf16
    const float* __restrict__ bias,         // [N] or null
    const float* __restrict__ cmT,          // [HD][S] (MODE 1)
    const float* __restrict__ smT,
    float* __restrict__ Cout,               // MODE 0
    unsigned short* __restrict__ qr,        // MODE 1: [NH][S][HD]
    unsigned short* __restrict__ kr,        // MODE 1: [NKV][S][HD]
    unsigned short* __restrict__ vt,        // MODE 1: [NKVD][S]
    int M, int N, int K) {
  __shared__ __align__(16) unsigned short As[128 * 64];
  __shared__ __align__(16) unsigned short Bs[128 * 64];
  const int tid = threadIdx.x, wave = tid >> 6;
  const int lane = tid & 63, quad = lane >> 4, l16 = lane & 15;
  const int bm = blockIdx.y * 128, bn = blockIdx.x * 128;
  const int wrow = (wave >> 1) * 64, wc2 = (wave & 1) * 32;
  f32x4 acc[4][4] = {};
  for (int k0 = 0; k0 < K; k0 += 64) {
#pragma unroll
    for (int t = 0; t < 4; ++t) {
      int g = t * 256 + tid;                 // chunk 0..1023
      int row = g >> 3;
      int c = (g & 7) ^ (row & 7);           // logical k-chunk to fetch
      async_cp16(&A[(size_t)(bm + row) * K + k0 + c * 8], &As[(size_t)g * 8]);
      async_cp16(&Bt[(size_t)(bn + row) * K + k0 + c * 8], &Bs[(size_t)g * 8]);
    }
    __syncthreads();
    bf16x8 af[4][2], bfr[4][2];
#pragma unroll
    for (int i = 0; i < 4; ++i) {
      int ra = wrow + i * 16 + l16;
#pragma unroll
      for (int ks = 0; ks < 2; ++ks)
        af[i][ks] = ld_frag(&As[ra * 64 + (((ks * 4 + quad) ^ (ra & 7)) << 3)]);
    }
#pragma unroll
    for (int j = 0; j < 4; ++j) {
      int rb = wc2 + (j & 1) * 16 + (j >> 1) * 64 + l16;
#pragma unroll
      for (int ks = 0; ks < 2; ++ks)
        bfr[j][ks] = ld_frag(&Bs[rb * 64 + (((ks * 4 + quad) ^ (rb & 7)) << 3)]);
    }
#pragma unroll
    for (int ks = 0; ks < 2; ++ks)
#pragma unroll
      for (int i = 0; i < 4; ++i)
#pragma unroll
        for (int j = 0; j < 4; ++j)
          acc[i][j] = __builtin_amdgcn_mfma_f32_16x16x32_bf16(af[i][ks], bfr[j][ks],
                                                              acc[i][j], 0, 0, 0);
    __syncthreads();
  }
  int dcol[4];
  float bj[4];
#pragma unroll
  for (int j = 0; j < 4; ++j) {
    dcol[j] = wc2 + (j & 1) * 16 + (j >> 1) * 64 + l16;
    bj[j] = bias ? bias[bn + dcol[j]] : 0.f;
  }
  if (MODE == 0) {
#pragma unroll
    for (int i = 0; i < 4; ++i) {
      int row0 = bm + wrow + i * 16 + quad * 4;
#pragma unroll
      for (int j = 0; j < 4; ++j)
#pragma unroll
        for (int r = 0; r < 4; ++r)
          Cout[(size_t)(row0 + r) * N + bn + dcol[j]] = acc[i][j][r] + bj[j];
    }
  } else {
    const int tile = blockIdx.x;  // 0..27 q head | 28..31 k head | 32..35 v head
    if (tile < 32) {
      const bool isq = tile < 28;
      unsigned short* dst = isq ? (qr + (size_t)tile * S_LEN * HD)
                                : (kr + (size_t)(tile - 28) * S_LEN * HD);
      const float scl = isq ? QSCALE : 1.0f;
#pragma unroll
      for (int i = 0; i < 4; ++i) {
        int srow = bm + wrow + i * 16 + quad * 4;
#pragma unroll
        for (int j = 0; j < 4; ++j) {
          int d = dcol[j];
          f32x4 cm4 = *(const f32x4*)&cmT[(size_t)d * S_LEN + srow];
          f32x4 sm4 = *(const f32x4*)&smT[(size_t)d * S_LEN + srow];
#pragma unroll
          for (int r = 0; r < 4; ++r) {
            float x = acc[i][j][r] + bj[j];
            float px = acc[i][j ^ 2][r] + bj[j ^ 2];
            float pr = (j < 2) ? -px : px;   // rotate_half partner (d^64, same lane)
            dst[(size_t)(srow + r) * HD + d] = f2bf((x * cm4[r] + pr * sm4[r]) * scl);
          }
        }
      }
    } else {
      const int kvh = tile - 32;
#pragma unroll
      for (int i = 0; i < 4; ++i) {
        int srow = bm + wrow + i * 16 + quad * 4;
#pragma unroll
        for (int j = 0; j < 4; ++j) {
          int d = dcol[j];
          unsigned w0 = (unsigned)f2bf(acc[i][j][0] + bj[j]) |
                        ((unsigned)f2bf(acc[i][j][1] + bj[j]) << 16);
          unsigned w1 = (unsigned)f2bf(acc[i][j][2] + bj[j]) |
                        ((unsigned)f2bf(acc[i][j][3] + bj[j]) << 16);
          unsigned short* vp = &vt[(size_t)(kvh * HD + d) * S_LEN + srow];
          *(unsigned*)vp = w0;
          *(unsigned*)(vp + 2) = w1;
        }
      }
    }
  }
}

// ---------------- flash attention v3 ----------------
// block = 128 threads (2 waves); each wave owns 32 q (2 strips of 16); block = 64 q.
// K/V tiles (64 KV rows) shared: K-frags and V-frags loaded once per wave, reused by
// both strips -> LDS bytes/MFMA halved vs v2. PV uses 16x16x16 MFMA so P stays in
// registers (C-layout row=quad*4+r == B-operand k=quad*4+j). Tile-0 max, RTZ-P.
__global__ __launch_bounds__(128, 3) void attn3(
    const unsigned short* __restrict__ Q,   // [NH][S][HD] bf16, pre-scaled by QSCALE
    const unsigned short* __restrict__ Kh,  // [NKV][S][HD] bf16
    const unsigned short* __restrict__ Vt,  // [NKVD][S] bf16 (d-major)
    unsigned short* __restrict__ O) {       // [S][NQD] bf16
  __shared__ __align__(16) unsigned short Ks[64 * 128];
  __shared__ __align__(16) unsigned short Vs[128 * 64];
  const int tid = threadIdx.x, wave = tid >> 6, lane = tid & 63;
  const int quad = lane >> 4, l16 = lane & 15;
  const int b = blockIdx.x;
  const int xcd = b & 7, slot = b >> 3;
  const int kvh = xcd & 3;
  const int strip = (xcd >> 2) * 112 + slot;
  const int h = kvh * 7 + (strip >> 5);
  const int qt = strip & 31;
  // Q for 2 strips, B-operand frags
  bf16x8 qf[2][4];
#pragma unroll
  for (int s2 = 0; s2 < 2; ++s2) {
    const size_t qrow = ((size_t)h * S_LEN + qt * 64 + wave * 32 + s2 * 16 + l16) * HD;
#pragma unroll
    for (int kc = 0; kc < 4; ++kc)
      qf[s2][kc] = ld_frag(&Q[qrow + kc * 32 + quad * 8]);
  }
  f32x4 accO[2][8] = {};
  float m[2] = {0.f, 0.f}, lsum[2] = {0.f, 0.f};
  for (int kt = 0; kt < S_LEN / 64; ++kt) {
    // stage K (1024 chunks) + V (1024 chunks), 16 cp16/lane over 128 lanes
#pragma unroll
    for (int t = 0; t < 8; ++t) {
      int g = t * 128 + tid;
      int krow = g >> 4, kq = ((g & 15) ^ (krow & 15)) * 8;
      async_cp16(&Kh[((size_t)kvh * S_LEN + kt * 64 + krow) * HD + kq], &Ks[(size_t)g * 8]);
      int vrow = g >> 3, vc = ((g & 7) ^ (vrow & 7)) * 8;
      async_cp16(&Vt[((size_t)(kvh * HD) + vrow) * S_LEN + kt * 64 + vc], &Vs[(size_t)g * 8]);
    }
    __syncthreads();
    // S^T = K.Q^T : K-frags shared across both strips
    f32x4 st[2][4] = {};
#pragma unroll
    for (int s4 = 0; s4 < 4; ++s4) {
      int row = s4 * 16 + l16;
      bf16x8 a[4];
#pragma unroll
      for (int kc = 0; kc < 4; ++kc)
        a[kc] = ld_frag(&Ks[row * 128 + (((kc * 4 + quad) ^ (row & 15)) << 3)]);
#pragma unroll
      for (int s2 = 0; s2 < 2; ++s2)
#pragma unroll
        for (int kc = 0; kc < 4; ++kc)
          st[s2][s4] = __builtin_amdgcn_mfma_f32_16x16x32_bf16(a[kc], qf[s2][kc],
                                                               st[s2][s4], 0, 0, 0);
    }
    // softmax per strip (tile-0 max; RTZ-truncated P, sum of same values)
    unsigned pbd[2][4][2];
#pragma unroll
    for (int s2 = 0; s2 < 2; ++s2) {
      if (kt == 0) {
        float mt = st[s2][0][0];
#pragma unroll
        for (int s4 = 0; s4 < 4; ++s4)
#pragma unroll
          for (int r = 0; r < 4; ++r) mt = fmaxf(mt, st[s2][s4][r]);
        mt = fmaxf(mt, __shfl_xor(mt, 16));
        mt = fmaxf(mt, __shfl_xor(mt, 32));
        m[s2] = mt;
      }
      float sum = 0.f;
#pragma unroll
      for (int s4 = 0; s4 < 4; ++s4) {
        unsigned u0 = __builtin_bit_cast(unsigned, exp2f(st[s2][s4][0] - m[s2])) & 0xffff0000u;
        unsigned u1 = __builtin_bit_cast(unsigned, exp2f(st[s2][s4][1] - m[s2])) & 0xffff0000u;
        unsigned u2 = __builtin_bit_cast(unsigned, exp2f(st[s2][s4][2] - m[s2])) & 0xffff0000u;
        unsigned u3 = __builtin_bit_cast(unsigned, exp2f(st[s2][s4][3] - m[s2])) & 0xffff0000u;
        sum += __builtin_bit_cast(float, u0) + __builtin_bit_cast(float, u1) +
               __builtin_bit_cast(float, u2) + __builtin_bit_cast(float, u3);
        pbd[s2][s4][0] = (u0 >> 16) | u1;   // bf16 pair (r0,r1) = k (quad*4+0, +1)
        pbd[s2][s4][1] = (u2 >> 16) | u3;   // bf16 pair (r2,r3)
      }
      sum += __shfl_xor(sum, 16);
      sum += __shfl_xor(sum, 32);
      lsum[s2] += sum;
    }
    // O^T += Vt.P via 16x16x16: V A-frag (ds_read_b64) shared across both strips
#pragma unroll
    for (int dt = 0; dt < 8; ++dt) {
      int row = dt * 16 + l16;
#pragma unroll
      for (int c = 0; c < 4; ++c) {
        int plog = c * 2 + (quad >> 1);
        int eoff = ((plog ^ (row & 7)) << 3) + ((quad & 1) << 2);
        uint2 av = *(const uint2*)&Vs[row * 64 + eoff];
#pragma unroll
        for (int s2 = 0; s2 < 2; ++s2)
          accO[s2][dt] = mfma16(av.x, av.y, pbd[s2][c][0], pbd[s2][c][1], accO[s2][dt]);
      }
    }
    __syncthreads();
  }
  // epilogue per strip: accO col=l16=q, row=quad*4+r=d_local
#pragma unroll
  for (int s2 = 0; s2 < 2; ++s2) {
    float rl = 1.f / lsum[s2];
    const size_t orow =
        ((size_t)(qt * 64 + wave * 32 + s2 * 16 + l16)) * NQD + h * HD;
#pragma unroll
    for (int dt = 0; dt < 8; ++dt) {
      unsigned w0 = (unsigned)f2bf(accO[s2][dt][0] * rl) |
                    ((unsigned)f2bf(accO[s2][dt][1] * rl) << 16);
      unsigned w1 = (unsigned)f2bf(accO[s2][dt][2] * rl) |
                    ((unsigned)f2bf(accO[s2][dt][3] * rl) << 16);
      *(unsigned*)&O[orow + dt * 16 + quad * 4] = w0;
      *(unsigned*)&O[orow + dt * 16 + quad * 4 + 2] = w1;
    }
  }
}

extern "C" void kernel_launch(void* const* d_in, const int* in_sizes, int n_in,
                              void* d_out, int out_size, void* d_ws, size_t ws_size,
                              hipStream_t stream) {
  const float* hidden = (const float*)d_in[0];
  const float* cosp = (const float*)d_in[1];
  const float* sinp = (const float*)d_in[2];
  const float* Wq = (const float*)d_in[3];
  const float* bq = (const float*)d_in[4];
  const float* Wk = (const float*)d_in[5];
  const float* bk = (const float*)d_in[6];
  const float* Wv = (const float*)d_in[7];
  const float* bv = (const float*)d_in[8];
  const float* Wo = (const float*)d_in[9];
  float* out = (float*)d_out;

  const size_t HID_N = (size_t)S_LEN * HDIM;
  const size_t WQ_N = (size_t)HDIM * NQD;
  const size_t KV_N = (size_t)S_LEN * NKVD;

  char* p = (char*)d_ws;
  size_t off = 0;
  auto take = [&](size_t bytes) {
    void* r = p + off; off += (bytes + 255) & ~(size_t)255; return r;
  };
  unsigned short* hid_bf = (unsigned short*)take(HID_N * 2);
  unsigned short* wqkvT = (unsigned short*)take((size_t)NQKV * HDIM * 2);
  unsigned short* woT = (unsigned short*)take(WQ_N * 2);
  float* bcat = (float*)take(NQKV * 4);
  float* cmT = (float*)take((size_t)HD * S_LEN * 4);
  float* smT = (float*)take((size_t)HD * S_LEN * 4);
  unsigned short* q_rot = (unsigned short*)take(HID_N * 2);
  unsigned short* k_rot = (unsigned short*)take(KV_N * 2);
  unsigned short* v_t = (unsigned short*)take(KV_N * 2);
  unsigned short* attn_bf = (unsigned short*)take(HID_N * 2);
  if (off > ws_size) return;   // loud failure: output stays poisoned

  cvt_kernel<<<(int)((HID_N / 4 + 255) / 256), 256, 0, stream>>>(hidden, hid_bf, (int)(HID_N / 4));
  dim3 tb(32, 8);
  tcvt<<<dim3(NQD / 32, HDIM / 32), tb, 0, stream>>>(Wq, wqkvT, HDIM, NQD, NQD);
  tcvt<<<dim3(NKVD / 32, HDIM / 32), tb, 0, stream>>>(Wk, wqkvT + (size_t)NQD * HDIM, HDIM, NKVD, NKVD);
  tcvt<<<dim3(NKVD / 32, HDIM / 32), tb, 0, stream>>>(Wv, wqkvT + (size_t)(NQD + NKVD) * HDIM, HDIM, NKVD, NKVD);
  tcvt<<<dim3(NQD / 32, NQD / 32), tb, 0, stream>>>(Wo, woT, NQD, NQD, NQD);
  biascat<<<(NQKV + 255) / 256, 256, 0, stream>>>(bq, bk, bv, bcat);
  tcs_kernel<<<dim3(S_LEN / 32, HD / 32), tb, 0, stream>>>(cosp, sinp, cmT, smT);

  // fused QKV projection + rope + head-major/transposed stores
  gemm_k64<1><<<dim3(NQKV / 128, S_LEN / 128), 256, 0, stream>>>(
      hid_bf, wqkvT, bcat, cmT, smT, nullptr, q_rot, k_rot, v_t, S_LEN, NQKV, HDIM);
  // attention
  attn3<<<NH * (S_LEN / 64), 128, 0, stream>>>(q_rot, k_rot, v_t, attn_bf);
  // output projection
  gemm_k64<0><<<dim3(NQD / 128, S_LEN / 128), 256, 0, stream>>>(
      attn_bf, woT, nullptr, nullptr, nullptr, out, nullptr, nullptr, nullptr,
      S_LEN, NQD, NQD);
}